// Round 1
// baseline (320.547 us; speedup 1.0000x reference)
//
#include <hip/hip_runtime.h>
#include <math.h>

#define B_ 16
#define H_ 8
#define D_ 128
#define BS_ 16
#define BPS_ 128
#define T_ (BPS_ * BS_)       // 2048 tokens per sequence
#define NSPLIT 8
#define CHUNK (T_ / NSPLIT)   // 256 tokens per chunk
#define SCALE_ 0.08838834764831845f

// Kernel 1: per-(b, h, chunk) partial attention with chunk-local softmax.
// Writes (m, l, O[128]) per chunk to workspace.
__global__ __launch_bounds__(256) void attn_partial(
    const float* __restrict__ q,
    const float* __restrict__ knew,
    const float* __restrict__ vnew,
    const float* __restrict__ kc,
    const float* __restrict__ vc,
    const int* __restrict__ btab,
    const int* __restrict__ clen,
    float* __restrict__ ws_m,
    float* __restrict__ ws_l,
    float* __restrict__ ws_o)
{
    const int c = blockIdx.x;   // chunk
    const int h = blockIdx.y;
    const int b = blockIdx.z;
    const int tid = threadIdx.x;
    const int wave = tid >> 6;
    const int lane = tid & 63;
    const int hl = lane & 31;   // lane within half-wave
    const int half = lane >> 5; // which half-wave (token selector)
    const int ctx = clen[b];
    const int chunk_start = c * CHUNK;

    __shared__ float s_p[CHUNK];     // scores -> probs
    __shared__ float s_red[8];       // per-wave reduction scratch
    __shared__ float s_o[4][D_];     // per-wave output partials
    __shared__ float s_ml[2];        // chunk m, l

    // q fragment for QK phase: float4 at d = 4*hl (half-wave covers 128 dims)
    const float4 q4 = *(const float4*)(q + ((size_t)b * H_ + h) * D_ + 4 * hl);

    // ---- QK phase: each wave handles 64 tokens, 2 per iteration (one per half-wave)
    for (int it = 0; it < 32; ++it) {
        const int tl = wave * 64 + it * 2 + half;   // local token in chunk
        const int tg = chunk_start + tl;            // global token index
        const int blk = btab[b * BPS_ + (tg >> 4)];
        const float* kp = (tg == ctx - 1)
            ? (knew + ((size_t)b * H_ + h) * D_)
            : (kc + (((size_t)blk * BS_ + (tg & 15)) * H_ + h) * D_);
        const float4 k4 = *(const float4*)(kp + 4 * hl);
        float s = q4.x * k4.x + q4.y * k4.y + q4.z * k4.z + q4.w * k4.w;
        // half-wave butterfly reduce (xor offsets < 32 stay within each half)
        s += __shfl_xor(s, 16);
        s += __shfl_xor(s, 8);
        s += __shfl_xor(s, 4);
        s += __shfl_xor(s, 2);
        s += __shfl_xor(s, 1);
        if (hl == 0) s_p[tl] = (tg < ctx) ? s * SCALE_ : -INFINITY;
    }
    __syncthreads();

    // ---- chunk max
    float sc = s_p[tid];
    float m = sc;
    m = fmaxf(m, __shfl_xor(m, 32));
    m = fmaxf(m, __shfl_xor(m, 16));
    m = fmaxf(m, __shfl_xor(m, 8));
    m = fmaxf(m, __shfl_xor(m, 4));
    m = fmaxf(m, __shfl_xor(m, 2));
    m = fmaxf(m, __shfl_xor(m, 1));
    if (lane == 0) s_red[wave] = m;
    __syncthreads();
    if (tid == 0) {
        float mm = fmaxf(fmaxf(s_red[0], s_red[1]), fmaxf(s_red[2], s_red[3]));
        s_ml[0] = fmaxf(mm, -1e30f);   // guard fully-masked chunk
    }
    __syncthreads();
    m = s_ml[0];

    // ---- exp + chunk sum
    float p = expf(sc - m);            // exp(-inf - m) = 0 for masked
    s_p[tid] = p;
    float l = p;
    l += __shfl_xor(l, 32);
    l += __shfl_xor(l, 16);
    l += __shfl_xor(l, 8);
    l += __shfl_xor(l, 4);
    l += __shfl_xor(l, 2);
    l += __shfl_xor(l, 1);
    if (lane == 0) s_red[4 + wave] = l;
    __syncthreads();
    if (tid == 0) s_ml[1] = s_red[4] + s_red[5] + s_red[6] + s_red[7];
    __syncthreads();

    // ---- PV phase: each wave accumulates 64 tokens; lane holds d = 2*lane, 2*lane+1
    float ox = 0.f, oy = 0.f;
    for (int it = 0; it < 64; ++it) {
        const int tl = wave * 64 + it;
        const int tg = chunk_start + tl;
        const float pw = s_p[tl];      // LDS broadcast
        const int blk = btab[b * BPS_ + (tg >> 4)];
        const float* vp = (tg == ctx - 1)
            ? (vnew + ((size_t)b * H_ + h) * D_)
            : (vc + (((size_t)blk * BS_ + (tg & 15)) * H_ + h) * D_);
        const float2 v2 = *(const float2*)(vp + 2 * lane);
        ox += pw * v2.x;
        oy += pw * v2.y;
    }
    s_o[wave][2 * lane]     = ox;
    s_o[wave][2 * lane + 1] = oy;
    __syncthreads();

    // ---- combine waves, write partials
    const int idx = (b * H_ + h) * NSPLIT + c;
    if (tid < D_) {
        float oo = s_o[0][tid] + s_o[1][tid] + s_o[2][tid] + s_o[3][tid];
        ws_o[(size_t)idx * D_ + tid] = oo;
    }
    if (tid == 0) {
        ws_m[idx] = s_ml[0];
        ws_l[idx] = s_ml[1];
    }
}

// Kernel 2: combine NSPLIT chunk partials per (b,h) with online-softmax rescale.
__global__ __launch_bounds__(128) void attn_reduce(
    const float* __restrict__ ws_m,
    const float* __restrict__ ws_l,
    const float* __restrict__ ws_o,
    float* __restrict__ out)
{
    const int bh = blockIdx.x;    // 0..127
    const int d = threadIdx.x;    // 0..127

    float mm[NSPLIT];
    float m_g = -INFINITY;
    for (int c = 0; c < NSPLIT; ++c) {
        mm[c] = ws_m[bh * NSPLIT + c];
        m_g = fmaxf(m_g, mm[c]);
    }
    float l_g = 0.f, acc = 0.f;
    for (int c = 0; c < NSPLIT; ++c) {
        const float co = expf(mm[c] - m_g);
        l_g += ws_l[bh * NSPLIT + c] * co;
        acc += ws_o[(size_t)(bh * NSPLIT + c) * D_ + d] * co;
    }
    out[(size_t)bh * D_ + d] = acc / l_g;
}

extern "C" void kernel_launch(void* const* d_in, const int* in_sizes, int n_in,
                              void* d_out, int out_size, void* d_ws, size_t ws_size,
                              hipStream_t stream) {
    const float* q    = (const float*)d_in[0];
    const float* knew = (const float*)d_in[1];
    const float* vnew = (const float*)d_in[2];
    const float* kc   = (const float*)d_in[3];
    const float* vc   = (const float*)d_in[4];
    // d_in[5] = slot_mapping: unused — slot == position of token ctx-1 in the
    // batch's own block table (disjoint rows), handled by in-flight substitution.
    const int* btab = (const int*)d_in[6];
    const int* clen = (const int*)d_in[7];
    float* out = (float*)d_out;

    float* ws   = (float*)d_ws;
    float* ws_m = ws;                        // B*H*NSPLIT floats
    float* ws_l = ws + B_ * H_ * NSPLIT;     // B*H*NSPLIT floats
    float* ws_o = ws + 2 * B_ * H_ * NSPLIT; // B*H*NSPLIT*D floats

    dim3 grid1(NSPLIT, H_, B_);
    attn_partial<<<grid1, 256, 0, stream>>>(q, knew, vnew, kc, vc, btab, clen,
                                            ws_m, ws_l, ws_o);
    attn_reduce<<<dim3(B_ * H_), D_, 0, stream>>>(ws_m, ws_l, ws_o, out);
}

// Round 2
// 309.141 us; speedup vs baseline: 1.0369x; 1.0369x over previous
//
#include <hip/hip_runtime.h>
#include <math.h>

#define B_ 16
#define H_ 8
#define D_ 128
#define BS_ 16
#define BPS_ 128
#define T_ (BPS_ * BS_)       // 2048 tokens per sequence
#define NSPLIT 16
#define CHUNK (T_ / NSPLIT)   // 128 tokens per chunk
#define NBLK_C (CHUNK / BS_)  // 8 cache blocks per chunk
#define SCALE_ 0.08838834764831845f

// Kernel 1: per-(b, h, chunk) partial attention with chunk-local softmax.
// Latency-hiding structure: block-table row pre-staged in LDS (no dependent
// global load in the address path), 4 independent 16B-wide loads in flight
// per wave in both QK and PV phases.
__global__ __launch_bounds__(256, 8) void attn_partial(
    const float* __restrict__ q,
    const float* __restrict__ knew,
    const float* __restrict__ vnew,
    const float* __restrict__ kc,
    const float* __restrict__ vc,
    const int* __restrict__ btab,
    const int* __restrict__ clen,
    float* __restrict__ ws_m,
    float* __restrict__ ws_l,
    float* __restrict__ ws_o)
{
    const int c = blockIdx.x;   // chunk
    const int h = blockIdx.y;
    const int b = blockIdx.z;
    const int tid = threadIdx.x;
    const int wave = tid >> 6;
    const int lane = tid & 63;
    const int hl = lane & 31;   // lane within half-wave (covers D via float4)
    const int half = lane >> 5; // half-wave = token selector
    const int ctx = clen[b];
    const int cs = c * CHUNK;

    __shared__ int   s_bt[NBLK_C];   // block ids for this chunk
    __shared__ float s_p[CHUNK];     // scores -> probs
    __shared__ float s_red[8];
    __shared__ float s_ml[2];
    __shared__ float s_o[8][D_];     // per-(wave,half) PV partials

    if (tid < NBLK_C) s_bt[tid] = btab[b * BPS_ + c * NBLK_C + tid];

    const float4 q4 = *(const float4*)(q + (size_t)(b * H_ + h) * D_ + 4 * hl);
    __syncthreads();

    // ---- QK phase: wave handles 32 tokens; 4 outer iters x (4 loads, then 4 reduces)
    #pragma unroll
    for (int o = 0; o < 4; ++o) {
        float4 k4[4];
        int tls[4];
        #pragma unroll
        for (int j = 0; j < 4; ++j) {
            const int tl = wave * 32 + o * 8 + j * 2 + half;
            tls[j] = tl;
            const int tg = cs + tl;
            const int blk = s_bt[tl >> 4];
            const float* kp = (tg == ctx - 1)
                ? (knew + (size_t)(b * H_ + h) * D_)
                : (kc + (((size_t)blk * BS_ + (tg & 15)) * H_ + h) * D_);
            k4[j] = *(const float4*)(kp + 4 * hl);
        }
        #pragma unroll
        for (int j = 0; j < 4; ++j) {
            float s = q4.x * k4[j].x + q4.y * k4[j].y + q4.z * k4[j].z + q4.w * k4[j].w;
            s += __shfl_xor(s, 16);
            s += __shfl_xor(s, 8);
            s += __shfl_xor(s, 4);
            s += __shfl_xor(s, 2);
            s += __shfl_xor(s, 1);
            if (hl == 0) s_p[tls[j]] = (cs + tls[j] < ctx) ? s * SCALE_ : -INFINITY;
        }
    }
    __syncthreads();

    // ---- chunk max over CHUNK=128 scores (waves 0-1)
    float sc = 0.f;
    if (tid < CHUNK) {
        sc = s_p[tid];
        float m = sc;
        m = fmaxf(m, __shfl_xor(m, 32));
        m = fmaxf(m, __shfl_xor(m, 16));
        m = fmaxf(m, __shfl_xor(m, 8));
        m = fmaxf(m, __shfl_xor(m, 4));
        m = fmaxf(m, __shfl_xor(m, 2));
        m = fmaxf(m, __shfl_xor(m, 1));
        if (lane == 0) s_red[wave] = m;
    }
    __syncthreads();
    if (tid == 0) s_ml[0] = fmaxf(fmaxf(s_red[0], s_red[1]), -1e30f);
    __syncthreads();
    const float m_c = s_ml[0];

    // ---- exp + chunk sum
    if (tid < CHUNK) {
        const float p = __expf(sc - m_c);   // exp(-inf - m) = 0 for masked
        s_p[tid] = p;
        float l = p;
        l += __shfl_xor(l, 32);
        l += __shfl_xor(l, 16);
        l += __shfl_xor(l, 8);
        l += __shfl_xor(l, 4);
        l += __shfl_xor(l, 2);
        l += __shfl_xor(l, 1);
        if (lane == 0) s_red[4 + wave] = l;
    }
    __syncthreads();
    if (tid == 0) s_ml[1] = s_red[4] + s_red[5];
    __syncthreads();

    // ---- PV phase: same half-wave float4 layout; 4 loads in flight
    float4 acc = make_float4(0.f, 0.f, 0.f, 0.f);
    #pragma unroll
    for (int o = 0; o < 4; ++o) {
        float4 v4[4];
        float pw[4];
        #pragma unroll
        for (int j = 0; j < 4; ++j) {
            const int tl = wave * 32 + o * 8 + j * 2 + half;
            const int tg = cs + tl;
            const int blk = s_bt[tl >> 4];
            const float* vp = (tg == ctx - 1)
                ? (vnew + (size_t)(b * H_ + h) * D_)
                : (vc + (((size_t)blk * BS_ + (tg & 15)) * H_ + h) * D_);
            v4[j] = *(const float4*)(vp + 4 * hl);
            pw[j] = s_p[tl];
        }
        #pragma unroll
        for (int j = 0; j < 4; ++j) {
            acc.x += pw[j] * v4[j].x;
            acc.y += pw[j] * v4[j].y;
            acc.z += pw[j] * v4[j].z;
            acc.w += pw[j] * v4[j].w;
        }
    }
    *(float4*)(&s_o[(wave << 1) | half][4 * hl]) = acc;
    __syncthreads();

    // ---- combine 8 partial rows, write chunk partials
    const int idx = (b * H_ + h) * NSPLIT + c;
    if (tid < D_) {
        float oo = 0.f;
        #pragma unroll
        for (int r = 0; r < 8; ++r) oo += s_o[r][tid];
        ws_o[(size_t)idx * D_ + tid] = oo;
    }
    if (tid == 0) {
        ws_m[idx] = s_ml[0];
        ws_l[idx] = s_ml[1];
    }
}

// Kernel 2: combine NSPLIT chunk partials per (b,h) with online-softmax rescale.
__global__ __launch_bounds__(128) void attn_reduce(
    const float* __restrict__ ws_m,
    const float* __restrict__ ws_l,
    const float* __restrict__ ws_o,
    float* __restrict__ out)
{
    const int bh = blockIdx.x;    // 0..127
    const int d = threadIdx.x;    // 0..127

    float mm[NSPLIT];
    float m_g = -INFINITY;
    #pragma unroll
    for (int c = 0; c < NSPLIT; ++c) {
        mm[c] = ws_m[bh * NSPLIT + c];
        m_g = fmaxf(m_g, mm[c]);
    }
    float l_g = 0.f, acc = 0.f;
    #pragma unroll
    for (int c = 0; c < NSPLIT; ++c) {
        const float co = __expf(mm[c] - m_g);
        l_g += ws_l[bh * NSPLIT + c] * co;
        acc += ws_o[(size_t)(bh * NSPLIT + c) * D_ + d] * co;
    }
    out[(size_t)bh * D_ + d] = acc / l_g;
}

extern "C" void kernel_launch(void* const* d_in, const int* in_sizes, int n_in,
                              void* d_out, int out_size, void* d_ws, size_t ws_size,
                              hipStream_t stream) {
    const float* q    = (const float*)d_in[0];
    const float* knew = (const float*)d_in[1];
    const float* vnew = (const float*)d_in[2];
    const float* kc   = (const float*)d_in[3];
    const float* vc   = (const float*)d_in[4];
    // d_in[5] = slot_mapping: unused — slot == position of token ctx-1 in the
    // batch's own block-table row (rows disjoint), handled by in-flight substitution.
    const int* btab = (const int*)d_in[6];
    const int* clen = (const int*)d_in[7];
    float* out = (float*)d_out;

    float* ws   = (float*)d_ws;
    float* ws_m = ws;                        // B*H*NSPLIT floats
    float* ws_l = ws + B_ * H_ * NSPLIT;     // B*H*NSPLIT floats
    float* ws_o = ws + 2 * B_ * H_ * NSPLIT; // B*H*NSPLIT*D floats (~1 MiB)

    dim3 grid1(NSPLIT, H_, B_);
    attn_partial<<<grid1, 256, 0, stream>>>(q, knew, vnew, kc, vc, btab, clen,
                                            ws_m, ws_l, ws_o);
    attn_reduce<<<dim3(B_ * H_), D_, 0, stream>>>(ws_m, ws_l, ws_o, out);
}

// Round 3
// 292.548 us; speedup vs baseline: 1.0957x; 1.0567x over previous
//
#include <hip/hip_runtime.h>
#include <math.h>

#define B_ 16
#define H_ 8
#define D_ 128
#define BS_ 16
#define BPS_ 128
#define T_ (BPS_ * BS_)       // 2048 tokens per sequence
#define ROW_ (H_ * D_)        // 1024 floats = 4 KiB per token row (all heads)
#define SCALE_ 0.08838834764831845f

// Kernel 1: WG = (chunk, batch), ALL 8 heads fused so K/V reads are fully
// contiguous 4-KiB token rows (HBM row-buffer friendly). One wave-wide
// float4 load = 1 KiB = 2 heads of one token; half-wave shuffle-reduce
// produces one score per (token, head).
template<int NS>
__global__ __launch_bounds__(256) void attn_partial(
    const float* __restrict__ q,
    const float* __restrict__ knew,
    const float* __restrict__ vnew,
    const float* __restrict__ kc,
    const float* __restrict__ vc,
    const int* __restrict__ btab,
    const int* __restrict__ clen,
    float* __restrict__ ws_m,
    float* __restrict__ ws_l,
    float* __restrict__ ws_o)
{
    constexpr int CHUNK = T_ / NS;        // tokens per WG
    constexpr int TPW = CHUNK / 4;        // tokens per wave
    constexpr int NBLK_C = CHUNK / BS_;   // cache blocks per chunk

    const int c = blockIdx.x;
    const int b = blockIdx.y;
    const int tid = threadIdx.x;
    const int wave = tid >> 6;
    const int lane = tid & 63;
    const int hl = lane & 31;    // lane within half-wave (covers one head: 32*16B=512B)
    const int half = lane >> 5;  // head parity within a load
    const int ctx = clen[b];
    const int cs = c * CHUNK;

    __shared__ int   s_bt[NBLK_C];
    __shared__ float s_p[H_][CHUNK];
    __shared__ float s_mx[H_], s_l[H_];
    __shared__ float s_o[4][H_][D_];     // 16 KiB per-wave PV partials

    if (tid < NBLK_C) s_bt[tid] = btab[b * BPS_ + c * NBLK_C + tid];

    // q row for this batch: 4 KiB; lane holds head (2j+half), dims 4*hl..4*hl+3
    float4 q4[4];
    #pragma unroll
    for (int j = 0; j < 4; ++j)
        q4[j] = *(const float4*)(q + (size_t)b * ROW_ + j * 256 + half * 128 + 4 * hl);
    __syncthreads();

    // ---- QK: wave handles tokens [wave*TPW, wave*TPW+TPW); 2 tokens (8 loads) in flight
    #pragma unroll 4
    for (int i = 0; i < TPW; i += 2) {
        float4 k4[8];
        #pragma unroll
        for (int u = 0; u < 2; ++u) {
            const int t = wave * TPW + i + u;
            const int tg = cs + t;
            const int blk = s_bt[t >> 4];
            const float* rb = (tg == ctx - 1)
                ? (knew + (size_t)b * ROW_)
                : (kc + ((size_t)blk * BS_ + (tg & 15)) * ROW_);
            #pragma unroll
            for (int j = 0; j < 4; ++j)
                k4[u * 4 + j] = *(const float4*)(rb + j * 256 + half * 128 + 4 * hl);
        }
        #pragma unroll
        for (int u = 0; u < 2; ++u) {
            const int t = wave * TPW + i + u;
            const int tg = cs + t;
            #pragma unroll
            for (int j = 0; j < 4; ++j) {
                const float4 kv = k4[u * 4 + j];
                float s = q4[j].x * kv.x + q4[j].y * kv.y + q4[j].z * kv.z + q4[j].w * kv.w;
                s += __shfl_xor(s, 16);
                s += __shfl_xor(s, 8);
                s += __shfl_xor(s, 4);
                s += __shfl_xor(s, 2);
                s += __shfl_xor(s, 1);
                if (hl == 0) s_p[2 * j + half][t] = (tg < ctx) ? s * SCALE_ : -INFINITY;
            }
        }
    }
    __syncthreads();

    // ---- per-head softmax stats: 32-lane group per head (h = tid>>5)
    {
        const int h = tid >> 5;
        float m = -INFINITY;
        for (int t = hl; t < CHUNK; t += 32) m = fmaxf(m, s_p[h][t]);
        m = fmaxf(m, __shfl_xor(m, 16));
        m = fmaxf(m, __shfl_xor(m, 8));
        m = fmaxf(m, __shfl_xor(m, 4));
        m = fmaxf(m, __shfl_xor(m, 2));
        m = fmaxf(m, __shfl_xor(m, 1));
        if (hl == 0) s_mx[h] = fmaxf(m, -1e30f);
    }
    __syncthreads();
    {
        const int h = tid >> 5;
        const float mx = s_mx[h];
        float l = 0.f;
        for (int t = hl; t < CHUNK; t += 32) {
            const float p = __expf(s_p[h][t] - mx);  // masked -> exp(-inf)=0
            s_p[h][t] = p;
            l += p;
        }
        l += __shfl_xor(l, 16);
        l += __shfl_xor(l, 8);
        l += __shfl_xor(l, 4);
        l += __shfl_xor(l, 2);
        l += __shfl_xor(l, 1);
        if (hl == 0) s_l[h] = l;
    }
    __syncthreads();

    // ---- PV: same contiguous row loads; acc[j] = head (2j+half), dims 4*hl..+3
    float4 acc[4];
    #pragma unroll
    for (int j = 0; j < 4; ++j) acc[j] = make_float4(0.f, 0.f, 0.f, 0.f);
    #pragma unroll 4
    for (int i = 0; i < TPW; i += 2) {
        float4 v4[8];
        #pragma unroll
        for (int u = 0; u < 2; ++u) {
            const int t = wave * TPW + i + u;
            const int tg = cs + t;
            const int blk = s_bt[t >> 4];
            const float* rb = (tg == ctx - 1)
                ? (vnew + (size_t)b * ROW_)
                : (vc + ((size_t)blk * BS_ + (tg & 15)) * ROW_);
            #pragma unroll
            for (int j = 0; j < 4; ++j)
                v4[u * 4 + j] = *(const float4*)(rb + j * 256 + half * 128 + 4 * hl);
        }
        #pragma unroll
        for (int u = 0; u < 2; ++u) {
            const int t = wave * TPW + i + u;
            #pragma unroll
            for (int j = 0; j < 4; ++j) {
                const float pw = s_p[2 * j + half][t];   // LDS broadcast
                acc[j].x += pw * v4[u * 4 + j].x;
                acc[j].y += pw * v4[u * 4 + j].y;
                acc[j].z += pw * v4[u * 4 + j].z;
                acc[j].w += pw * v4[u * 4 + j].w;
            }
        }
    }
    #pragma unroll
    for (int j = 0; j < 4; ++j)
        *(float4*)&s_o[wave][2 * j + half][4 * hl] = acc[j];
    __syncthreads();

    // ---- combine 4 waves, write chunk partials
    for (int r = tid; r < H_ * D_; r += 256) {
        const int h = r >> 7, d = r & 127;
        const float oo = s_o[0][h][d] + s_o[1][h][d] + s_o[2][h][d] + s_o[3][h][d];
        ws_o[((size_t)(b * H_ + h) * NS + c) * D_ + d] = oo;
    }
    if (tid < H_) {
        ws_m[(b * H_ + tid) * NS + c] = s_mx[tid];
        ws_l[(b * H_ + tid) * NS + c] = s_l[tid];
    }
}

// Kernel 2: combine NS chunk partials per (b,h) with online-softmax rescale.
template<int NS>
__global__ __launch_bounds__(128) void attn_reduce(
    const float* __restrict__ ws_m,
    const float* __restrict__ ws_l,
    const float* __restrict__ ws_o,
    float* __restrict__ out)
{
    const int bh = blockIdx.x;    // 0..127
    const int tid = threadIdx.x;  // 0..127 = d

    __shared__ float s_co[NS];
    __shared__ float s_lg;

    if (tid < 64) {
        float m = -INFINITY;
        for (int cc = tid; cc < NS; cc += 64) m = fmaxf(m, ws_m[bh * NS + cc]);
        m = fmaxf(m, __shfl_xor(m, 32));
        m = fmaxf(m, __shfl_xor(m, 16));
        m = fmaxf(m, __shfl_xor(m, 8));
        m = fmaxf(m, __shfl_xor(m, 4));
        m = fmaxf(m, __shfl_xor(m, 2));
        m = fmaxf(m, __shfl_xor(m, 1));   // m = global max, all lanes
        float lw = 0.f;
        for (int cc = tid; cc < NS; cc += 64) {
            const float co = __expf(ws_m[bh * NS + cc] - m);
            s_co[cc] = co;
            lw += ws_l[bh * NS + cc] * co;
        }
        lw += __shfl_xor(lw, 32);
        lw += __shfl_xor(lw, 16);
        lw += __shfl_xor(lw, 8);
        lw += __shfl_xor(lw, 4);
        lw += __shfl_xor(lw, 2);
        lw += __shfl_xor(lw, 1);
        if (tid == 0) s_lg = lw;
    }
    __syncthreads();

    float acc = 0.f;
    #pragma unroll 8
    for (int cc = 0; cc < NS; ++cc)
        acc += s_co[cc] * ws_o[((size_t)bh * NS + cc) * D_ + tid];
    out[(size_t)bh * D_ + tid] = acc / s_lg;
}

template<int NS>
static void launch_all(const float* q, const float* knew, const float* vnew,
                       const float* kc, const float* vc,
                       const int* btab, const int* clen,
                       float* ws, float* out, hipStream_t stream)
{
    float* ws_m = ws;
    float* ws_l = ws + B_ * H_ * NS;
    float* ws_o = ws + 2 * B_ * H_ * NS;
    attn_partial<NS><<<dim3(NS, B_), 256, 0, stream>>>(q, knew, vnew, kc, vc,
                                                       btab, clen, ws_m, ws_l, ws_o);
    attn_reduce<NS><<<dim3(B_ * H_), 128, 0, stream>>>(ws_m, ws_l, ws_o, out);
}

extern "C" void kernel_launch(void* const* d_in, const int* in_sizes, int n_in,
                              void* d_out, int out_size, void* d_ws, size_t ws_size,
                              hipStream_t stream) {
    const float* q    = (const float*)d_in[0];
    const float* knew = (const float*)d_in[1];
    const float* vnew = (const float*)d_in[2];
    const float* kc   = (const float*)d_in[3];
    const float* vc   = (const float*)d_in[4];
    // d_in[5] = slot_mapping: unused — slot == position of token ctx-1 in the
    // batch's own block-table row (rows disjoint), handled by in-flight substitution.
    const int* btab = (const int*)d_in[6];
    const int* clen = (const int*)d_in[7];
    float* out = (float*)d_out;
    float* ws  = (float*)d_ws;

    // scratch need for split NS: B*H*NS*(2 + D) floats
    const size_t need64 = (size_t)B_ * H_ * 64 * (2 + D_) * sizeof(float); // ~4.1 MiB
    const size_t need32 = (size_t)B_ * H_ * 32 * (2 + D_) * sizeof(float);
    if (ws_size >= need64)      launch_all<64>(q, knew, vnew, kc, vc, btab, clen, ws, out, stream);
    else if (ws_size >= need32) launch_all<32>(q, knew, vnew, kc, vc, btab, clen, ws, out, stream);
    else                        launch_all<16>(q, knew, vnew, kc, vc, btab, clen, ws, out, stream);
}